// Round 19
// baseline (197.168 us; speedup 1.0000x reference)
//
#include <hip/hip_runtime.h>
#include <cstddef>
#include <cstdint>

#define RR 16384   // B*N rows
#define CC 256
#define NN 2048

typedef __attribute__((ext_vector_type(8))) _Float16 h8;
typedef __attribute__((ext_vector_type(4))) float float4v;
typedef __attribute__((ext_vector_type(8))) unsigned short u16x8;
typedef unsigned short u16;

__device__ inline float h2f(u16 u) {
  return (float)__builtin_bit_cast(_Float16, u);
}
__device__ inline u16 f2h(float f) {
  return __builtin_bit_cast(u16, (_Float16)f);
}

// ---------------------------------------------------------------------------
// Combined init: weight splits (bid < 3072) + LN1-split (bid >= 3072).
__global__ __launch_bounds__(256) void init_all(const float* __restrict__ wq,
    const float* __restrict__ wk, const float* __restrict__ wv,
    const float* __restrict__ wo, const float* __restrict__ w1,
    const float* __restrict__ w2, u16* __restrict__ Wqkv,
    u16* __restrict__ wo2, u16* __restrict__ w12, u16* __restrict__ w22,
    const float* __restrict__ x, const float* __restrict__ ln1g,
    const float* __restrict__ ln1b, u16* __restrict__ h1s) {
  const int bid = blockIdx.x;
  if (bid < 768) {  // QKV 3-term, K=256
    const float* W = (bid < 256) ? wq : (bid < 512) ? wk : wv;
    const int rowoff = (bid >> 8) << 8;
    const int li = (bid & 255) * 256 + threadIdx.x;
    const int o = li >> 8, k = li & 255;
    const float w = W[li];
    const u16 h1 = f2h(w);
    const u16 h2 = f2h(w - h2f(h1));
    u16* base = Wqkv + (size_t)(o + rowoff) * 768;
    base[k] = h1; base[256 + k] = h1; base[512 + k] = h2;
  } else if (bid < 1024) {  // wo 1-term
    const int li = (bid - 768) * 256 + threadIdx.x;
    wo2[li] = f2h(wo[li]);
  } else if (bid < 2048) {  // w1 1-term
    const int li = (bid - 1024) * 256 + threadIdx.x;
    w12[li] = f2h(w1[li]);
  } else if (bid < 3072) {  // w2 1-term
    const int li = (bid - 2048) * 256 + threadIdx.x;
    w22[li] = f2h(w2[li]);
  } else {  // LN1 -> split f16 [hi|lo]
    const int wave = threadIdx.x >> 6, lane = threadIdx.x & 63;
    const int row = ((bid - 3072) << 2) + wave;
    const float4 v = ((const float4*)(x + (size_t)row * CC))[lane];
    float s1 = v.x + v.y + v.z + v.w;
    float s2 = v.x * v.x + v.y * v.y + v.z * v.z + v.w * v.w;
#pragma unroll
    for (int o = 32; o > 0; o >>= 1) {
      s1 += __shfl_xor(s1, o);
      s2 += __shfl_xor(s2, o);
    }
    const float mu = s1 * (1.0f / CC);
    const float var = s2 * (1.0f / CC) - mu * mu;
    const float rs = 1.0f / sqrtf(var + 1e-5f);
    const float4 gg = ((const float4*)ln1g)[lane];
    const float4 bb = ((const float4*)ln1b)[lane];
    float o4[4];
    o4[0] = (v.x - mu) * rs * gg.x + bb.x;
    o4[1] = (v.y - mu) * rs * gg.y + bb.y;
    o4[2] = (v.z - mu) * rs * gg.z + bb.z;
    o4[3] = (v.w - mu) * rs * gg.w + bb.w;
    ushort4 hi, lo;
    hi.x = f2h(o4[0]); lo.x = f2h(o4[0] - h2f(hi.x));
    hi.y = f2h(o4[1]); lo.y = f2h(o4[1] - h2f(hi.y));
    hi.z = f2h(o4[2]); lo.z = f2h(o4[2] - h2f(hi.z));
    hi.w = f2h(o4[3]); lo.w = f2h(o4[3] - h2f(hi.w));
    *(ushort4*)(h1s + (size_t)row * 512 + (lane << 2)) = hi;
    *(ushort4*)(h1s + (size_t)row * 512 + 256 + (lane << 2)) = lo;
  }
}

// ---------------------------------------------------------------------------
// 8-wave 2-phase MFMA GEMM (proven skeleton).
template <int BM, int BN, int WM, int WN, int STATS, int MINW, int OUTF16,
          int LNFUSE>
__global__ __launch_bounds__(512, MINW) void gemm_sp(
    const u16* __restrict__ A, int AW,
    const u16* __restrict__ W2, int K2,
    const float* __restrict__ resid, void* __restrict__ Yv, int O,
    float* __restrict__ p1, float* __restrict__ p2,
    const float* __restrict__ lng, const float* __restrict__ lnb,
    u16* __restrict__ h2out) {
  constexpr int FM = BM / (WM * 16);
  constexpr int FN = BN / (WN * 16);
  constexpr int LA = BM / 64;
  constexpr int LB = BN / 64;
  constexpr int NL = LA + LB;
  static_assert(WM * WN == 8, "8 waves");
  static_assert(NL == 3 || NL == 4 || NL == 5 || NL == 7 || NL == 8,
                "vmcnt literal");
  static_assert(!LNFUSE || (BM == 64 && BN == 256), "LNFUSE tile");
  __shared__ __align__(16) u16 As[2][BM * 64];
  __shared__ __align__(16) u16 Bs[2][BN * 64];
  const int tid = threadIdx.x;
  const int lane = tid & 63, wid = tid >> 6;
  const int wr = wid / WN, wc = wid % WN;
  const int gx = gridDim.x;
  const int lid = blockIdx.y * gx + blockIdx.x;
  const int chunk = (gx * gridDim.y) >> 3;
  const int nid = (lid & 7) * chunk + (lid >> 3);
  const int bx = nid % gx, by = nid / gx;
  const int r0 = by * BM, o0 = bx * BN;
  const int lrow = tid >> 3;
  const int lce = ((tid & 7) ^ ((tid >> 3) & 7)) << 3;

  auto STAGE = [&](int buf, int kAs, int k0s) {
#pragma unroll
    for (int i = 0; i < LA; ++i) {
      const u16* srcA = A + (size_t)(r0 + i * 64 + lrow) * AW + kAs + lce;
      __builtin_amdgcn_global_load_lds(
          (const __attribute__((address_space(1))) void*)srcA,
          (__attribute__((address_space(3))) void*)&As[buf][(i * 64 + wid * 8) * 64],
          16, 0, 0);
    }
#pragma unroll
    for (int i = 0; i < LB; ++i) {
      const u16* srcB = W2 + (size_t)(o0 + i * 64 + lrow) * K2 + k0s + lce;
      __builtin_amdgcn_global_load_lds(
          (const __attribute__((address_space(1))) void*)srcB,
          (__attribute__((address_space(3))) void*)&Bs[buf][(i * 64 + wid * 8) * 64],
          16, 0, 0);
    }
  };

  float4v acc[FM][FN] = {};
  STAGE(0, 0, 0);
  int kA = 0, cur = 0;
  for (int k0 = 0; k0 < K2; k0 += 64) {
    const int kAn = (kA + 64) & (AW - 1);
    if (k0 + 64 < K2) {
      STAGE(cur ^ 1, kAn, k0 + 64);
      if constexpr (NL == 3)
        asm volatile("s_waitcnt vmcnt(3)\n\ts_barrier" ::: "memory");
      else if constexpr (NL == 4)
        asm volatile("s_waitcnt vmcnt(4)\n\ts_barrier" ::: "memory");
      else if constexpr (NL == 5)
        asm volatile("s_waitcnt vmcnt(5)\n\ts_barrier" ::: "memory");
      else if constexpr (NL == 7)
        asm volatile("s_waitcnt vmcnt(7)\n\ts_barrier" ::: "memory");
      else
        asm volatile("s_waitcnt vmcnt(8)\n\ts_barrier" ::: "memory");
    } else {
      asm volatile("s_waitcnt vmcnt(0)\n\ts_barrier" ::: "memory");
    }
#pragma unroll
    for (int kk = 0; kk < 2; ++kk) {
      h8 a[FM], b[FN];
      const int ch0 = (kk << 2) + (lane >> 4);
      const int chs = ch0 ^ (lane & 7);
#pragma unroll
      for (int m = 0; m < FM; ++m) {
        const int R = wr * (FM * 16) + m * 16 + (lane & 15);
        a[m] = *(const h8*)&As[cur][R * 64 + chs * 8];
      }
#pragma unroll
      for (int n = 0; n < FN; ++n) {
        const int Rb = wc * (FN * 16) + n * 16 + (lane & 15);
        b[n] = *(const h8*)&Bs[cur][Rb * 64 + chs * 8];
      }
#pragma unroll
      for (int m = 0; m < FM; ++m)
#pragma unroll
        for (int n = 0; n < FN; ++n)
          acc[m][n] = __builtin_amdgcn_mfma_f32_16x16x32_f16(a[m], b[n], acc[m][n], 0, 0, 0);
    }
    asm volatile("s_waitcnt lgkmcnt(0)\n\ts_barrier" ::: "memory");
    kA = kAn; cur ^= 1;
  }
  const int crow = (lane >> 4) << 2, ccol = lane & 15;
  float* ft = (float*)Bs;  // LNFUSE: 64x256 fp32 tile = 64KB
#pragma unroll
  for (int m = 0; m < FM; ++m)
#pragma unroll
    for (int n = 0; n < FN; ++n)
#pragma unroll
      for (int j = 0; j < 4; ++j) {
        const int lr = wr * (FM * 16) + (m << 4) + crow + j;
        const int lc = wc * (FN * 16) + (n << 4) + ccol;
        const size_t idx = (size_t)(r0 + lr) * O + o0 + lc;
        float v = acc[m][n][j];
        if constexpr (OUTF16) {
          ((u16*)Yv)[idx] = f2h(v);
        } else {
          if (resid) v += resid[idx];
          ((float*)Yv)[idx] = v;
        }
        if constexpr (LNFUSE) ft[lr * 256 + lc] = v;
      }
  if constexpr (LNFUSE) {
    __syncthreads();
    const int rr0 = wid << 3;
    const float4 gg = ((const float4*)lng)[lane];
    const float4 bb = ((const float4*)lnb)[lane];
#pragma unroll
    for (int rr = 0; rr < 8; ++rr) {
      const int r = rr0 + rr;
      const float4 v = ((const float4*)ft)[r * 64 + lane];
      float s1 = v.x + v.y + v.z + v.w;
      float s2 = v.x * v.x + v.y * v.y + v.z * v.z + v.w * v.w;
#pragma unroll
      for (int o = 32; o > 0; o >>= 1) {
        s1 += __shfl_xor(s1, o);
        s2 += __shfl_xor(s2, o);
      }
      const float mu = s1 * (1.0f / CC);
      const float var = s2 * (1.0f / CC) - mu * mu;
      const float rs = 1.0f / sqrtf(var + 1e-5f);
      ushort4 hh;
      hh.x = f2h((v.x - mu) * rs * gg.x + bb.x);
      hh.y = f2h((v.y - mu) * rs * gg.y + bb.y);
      hh.z = f2h((v.z - mu) * rs * gg.z + bb.z);
      hh.w = f2h((v.w - mu) * rs * gg.w + bb.w);
      *(ushort4*)(h2out + (size_t)(r0 + r) * 256 + (lane << 2)) = hh;
    }
  }
  if (STATS) {
    float s1[FN], s2[FN];
#pragma unroll
    for (int n = 0; n < FN; ++n) {
      s1[n] = 0.f; s2[n] = 0.f;
#pragma unroll
      for (int m = 0; m < FM; ++m)
#pragma unroll
        for (int j = 0; j < 4; ++j) {
          const float v = acc[m][n][j];
          s1[n] += v; s2[n] += v * v;
        }
    }
#pragma unroll
    for (int n = 0; n < FN; ++n) {
      s1[n] += __shfl_xor(s1[n], 16); s1[n] += __shfl_xor(s1[n], 32);
      s2[n] += __shfl_xor(s2[n], 16); s2[n] += __shfl_xor(s2[n], 32);
    }
    float* sb = (float*)As;
    __syncthreads();
    if (lane < 16) {
#pragma unroll
      for (int n = 0; n < FN; ++n) {
        const int cl = wc * (FN * 16) + n * 16 + lane;
        sb[wr * BN + cl] = s1[n];
        sb[WM * BN + wr * BN + cl] = s2[n];
      }
    }
    __syncthreads();
    if (tid < BN) {
      float a = 0.f, b = 0.f;
#pragma unroll
      for (int w = 0; w < WM; ++w) {
        a += sb[w * BN + tid];
        b += sb[WM * BN + w * BN + tid];
      }
      p1[(size_t)by * O + o0 + tid] = a;
      p2[(size_t)by * O + o0 + tid] = b;
    }
  }
}

// ---------------------------------------------------------------------------
// MLP2 with FUSED A-side spike (round-16 proven).
__global__ __launch_bounds__(512, 4) void gemm_mlp2f(
    const u16* __restrict__ A, const u16* __restrict__ W2,
    const float* __restrict__ sc, const float* __restrict__ sh,
    u16* __restrict__ Y, float* __restrict__ p1, float* __restrict__ p2) {
  constexpr int BM = 64, BN = 128, WM = 2, WN = 4, K2 = 1024;
  constexpr int FM = 2, FN = 2;
  __shared__ __align__(16) u16 As[2][BM * 64];
  __shared__ __align__(16) u16 Bs[2][BN * 64];
  const int tid = threadIdx.x;
  const int lane = tid & 63, wid = tid >> 6;
  const int wr = wid / WN, wc = wid % WN;
  const int gx = gridDim.x;
  const int lid = blockIdx.y * gx + blockIdx.x;
  const int chunk = (gx * gridDim.y) >> 3;
  const int nid = (lid & 7) * chunk + (lid >> 3);
  const int bx = nid % gx, by = nid / gx;
  const int r0 = by * BM, o0 = bx * BN;
  const int lrow = tid >> 3;
  const int cs = (tid & 7) ^ (lrow & 7);

  u16x8 a1, a2;
  float4 c01, c11, s01, s11, c02, c12, s02, s12;
  auto LOADA = [&](int k0s, u16x8& av, float4& c0, float4& c1, float4& s0,
                   float4& s1) {
    av = *(const u16x8*)(A + (size_t)(r0 + lrow) * 1024 + k0s + cs * 8);
    const int ch = k0s + cs * 8;
    c0 = *(const float4*)(sc + ch);
    c1 = *(const float4*)(sc + ch + 4);
    s0 = *(const float4*)(sh + ch);
    s1 = *(const float4*)(sh + ch + 4);
  };
  auto STAGE_B = [&](int buf, int k0s) {
#pragma unroll
    for (int i = 0; i < 2; ++i) {
      const u16* srcB = W2 + (size_t)(o0 + i * 64 + lrow) * K2 + k0s +
                        (((tid & 7) ^ (lrow & 7)) << 3);
      __builtin_amdgcn_global_load_lds(
          (const __attribute__((address_space(1))) void*)srcB,
          (__attribute__((address_space(3))) void*)&Bs[buf][(i * 64 + wid * 8) * 64],
          16, 0, 0);
    }
  };
  auto WRITEA = [&](int buf, u16x8 av, float4 c0, float4 c1, float4 s0,
                    float4 s1) {
    u16x8 sp;
    sp[0] = (h2f(av[0]) * c0.x + s0.x >= 1.0f) ? (u16)0x3C00 : (u16)0;
    sp[1] = (h2f(av[1]) * c0.y + s0.y >= 1.0f) ? (u16)0x3C00 : (u16)0;
    sp[2] = (h2f(av[2]) * c0.z + s0.z >= 1.0f) ? (u16)0x3C00 : (u16)0;
    sp[3] = (h2f(av[3]) * c0.w + s0.w >= 1.0f) ? (u16)0x3C00 : (u16)0;
    sp[4] = (h2f(av[4]) * c1.x + s1.x >= 1.0f) ? (u16)0x3C00 : (u16)0;
    sp[5] = (h2f(av[5]) * c1.y + s1.y >= 1.0f) ? (u16)0x3C00 : (u16)0;
    sp[6] = (h2f(av[6]) * c1.z + s1.z >= 1.0f) ? (u16)0x3C00 : (u16)0;
    sp[7] = (h2f(av[7]) * c1.w + s1.w >= 1.0f) ? (u16)0x3C00 : (u16)0;
    *(u16x8*)&As[buf][lrow * 64 + (tid & 7) * 8] = sp;
  };

  float4v acc[FM][FN] = {};
  LOADA(0, a1, c01, c11, s01, s11);
  STAGE_B(0, 0);
  int cur = 0;
  for (int k0 = 0; k0 < K2; k0 += 64) {
    if (k0 + 64 < K2) {
      LOADA(k0 + 64, a2, c02, c12, s02, s12);
      STAGE_B(cur ^ 1, k0 + 64);
      asm volatile("s_waitcnt vmcnt(7)\n\ts_barrier" ::: "memory");
    } else {
      asm volatile("s_waitcnt vmcnt(0)\n\ts_barrier" ::: "memory");
    }
    WRITEA(cur, a1, c01, c11, s01, s11);
    asm volatile("s_waitcnt lgkmcnt(0)\n\ts_barrier" ::: "memory");
#pragma unroll
    for (int kk = 0; kk < 2; ++kk) {
      h8 a[FM], b[FN];
      const int ch0 = (kk << 2) + (lane >> 4);
      const int chs = ch0 ^ (lane & 7);
#pragma unroll
      for (int m = 0; m < FM; ++m) {
        const int R = wr * 32 + m * 16 + (lane & 15);
        a[m] = *(const h8*)&As[cur][R * 64 + chs * 8];
      }
#pragma unroll
      for (int n = 0; n < FN; ++n) {
        const int Rb = wc * 32 + n * 16 + (lane & 15);
        b[n] = *(const h8*)&Bs[cur][Rb * 64 + chs * 8];
      }
#pragma unroll
      for (int m = 0; m < FM; ++m)
#pragma unroll
        for (int n = 0; n < FN; ++n)
          acc[m][n] = __builtin_amdgcn_mfma_f32_16x16x32_f16(a[m], b[n], acc[m][n], 0, 0, 0);
    }
    asm volatile("s_waitcnt lgkmcnt(0)\n\ts_barrier" ::: "memory");
    cur ^= 1;
    a1 = a2; c01 = c02; c11 = c12; s01 = s02; s11 = s12;
  }
  const int crow = (lane >> 4) << 2, ccol = lane & 15;
#pragma unroll
  for (int m = 0; m < FM; ++m)
#pragma unroll
    for (int n = 0; n < FN; ++n)
#pragma unroll
      for (int j = 0; j < 4; ++j) {
        const size_t idx =
            (size_t)(r0 + wr * 32 + (m << 4) + crow + j) * 256 +
            o0 + wc * 32 + (n << 4) + ccol;
        Y[idx] = f2h(acc[m][n][j]);
      }
  {  // STATS
    float s1[FN], s2[FN];
#pragma unroll
    for (int n = 0; n < FN; ++n) {
      s1[n] = 0.f; s2[n] = 0.f;
#pragma unroll
      for (int m = 0; m < FM; ++m)
#pragma unroll
        for (int j = 0; j < 4; ++j) {
          const float v = acc[m][n][j];
          s1[n] += v; s2[n] += v * v;
        }
    }
#pragma unroll
    for (int n = 0; n < FN; ++n) {
      s1[n] += __shfl_xor(s1[n], 16); s1[n] += __shfl_xor(s1[n], 32);
      s2[n] += __shfl_xor(s2[n], 16); s2[n] += __shfl_xor(s2[n], 32);
    }
    float* sb = (float*)As;
    __syncthreads();
    if (lane < 16) {
#pragma unroll
      for (int n = 0; n < FN; ++n) {
        const int cl = wc * 32 + n * 16 + lane;
        sb[wr * BN + cl] = s1[n];
        sb[WM * BN + wr * BN + cl] = s2[n];
      }
    }
    __syncthreads();
    if (tid < BN) {
      float a = 0.f, b = 0.f;
#pragma unroll
      for (int w = 0; w < WM; ++w) {
        a += sb[w * BN + tid];
        b += sb[WM * BN + w * BN + tid];
      }
      p1[(size_t)by * 256 + o0 + tid] = a;
      p2[(size_t)by * 256 + o0 + tid] = b;
    }
  }
}

// ---------------------------------------------------------------------------
// BN stats pass 2 (parallel). Optionally emits sc = rinv*g, sh = b - mu*rinv*g.
__global__ __launch_bounds__(256) void bn_stats2(const float* __restrict__ p1,
    const float* __restrict__ p2, float* __restrict__ mu,
    float* __restrict__ rinv, int O, int npanels,
    const float* __restrict__ g, const float* __restrict__ b,
    float* __restrict__ sc, float* __restrict__ sh) {
  const int c0 = blockIdx.x << 6;
  const int c = threadIdx.x & 63;
  const int jg = threadIdx.x >> 6;   // 0..3
  float s1 = 0.f, s2 = 0.f;
#pragma unroll 4
  for (int j = jg; j < npanels; j += 4) {
    s1 += p1[(size_t)j * O + c0 + c];
    s2 += p2[(size_t)j * O + c0 + c];
  }
  __shared__ float sb[8][64];
  sb[jg][c] = s1;
  sb[4 + jg][c] = s2;
  __syncthreads();
  if (threadIdx.x < 64) {
    const float a = ((sb[0][c] + sb[1][c]) + (sb[2][c] + sb[3][c]));
    const float bb = ((sb[4][c] + sb[5][c]) + (sb[6][c] + sb[7][c]));
    const float m = a * (1.0f / 16384.f);
    const float v = bb * (1.0f / 16384.f) - m * m;
    const float rv = 1.0f / sqrtf(v + 1e-5f);
    mu[c0 + c] = m;
    rinv[c0 + c] = rv;
    if (sc) {
      const float scale = rv * g[c0 + c];
      sc[c0 + c] = scale;
      sh[c0 + c] = b[c0 + c] - m * scale;
    }
  }
}

// BN affine + spike (f16 Y) added into fp32 output (final residual).
__global__ __launch_bounds__(256) void bn_spike_add_h16(
    const u16* __restrict__ Y, const float* __restrict__ mu,
    const float* __restrict__ rinv, const float* __restrict__ g,
    const float* __restrict__ b, float* __restrict__ addOut, int O) {
  const int i = blockIdx.x * 256 + threadIdx.x;
  const int c = (i << 2) & (O - 1);
  const ushort4 yh = ((const ushort4*)Y)[i];
  const float4 m4 = *(const float4*)(mu + c);
  const float4 r4 = *(const float4*)(rinv + c);
  const float4 g4 = *(const float4*)(g + c);
  const float4 b4 = *(const float4*)(b + c);
  float4 o4 = ((const float4*)addOut)[i];
  o4.x += ((h2f(yh.x) - m4.x) * r4.x * g4.x + b4.x >= 1.0f) ? 1.0f : 0.0f;
  o4.y += ((h2f(yh.y) - m4.y) * r4.y * g4.y + b4.y >= 1.0f) ? 1.0f : 0.0f;
  o4.z += ((h2f(yh.z) - m4.z) * r4.z * g4.z + b4.z >= 1.0f) ? 1.0f : 0.0f;
  o4.w += ((h2f(yh.w) - m4.w) * r4.w * g4.w + b4.w >= 1.0f) ? 1.0f : 0.0f;
  ((float4*)addOut)[i] = o4;
}

// ---------------------------------------------------------------------------
// M[b,h] = K^T V (64x64), split over n into 8 partials (integer-exact).
// Computes k/v channel BN stats inline from p1/p2 (replicates bn_stats2's
// exact summation order -> bit-identical mu/rinv).
__global__ __launch_bounds__(256) void attn_kv(const float* __restrict__ Yq,
    const float* __restrict__ p1, const float* __restrict__ p2,
    const float* __restrict__ kg, const float* __restrict__ kb,
    const float* __restrict__ vg, const float* __restrict__ vb,
    float* __restrict__ Mpart) {
  const int bh = blockIdx.x, sp = blockIdx.y;
  const int b = bh >> 2, h = bh & 3;
  const int t = threadIdx.x;
  const int gq = t >> 6, e = t & 63;
  __shared__ float ks[16][64], vs[16][64];
  __shared__ float ls1[4][128], ls2[4][128];
  __shared__ float smu[128], sriv[128];
  // --- stats for 128 local channels (k: 0..63 -> 256+h*64+cl; v: 64..127) ---
  {
    const int cl = t & 127;
    const int half = t >> 7;  // groups {0,1} or {2,3}
    const int cg = (cl < 64) ? (256 + (h << 6) + cl)
                             : (512 + (h << 6) + (cl - 64));
#pragma unroll
    for (int q = 0; q < 2; ++q) {
      const int g = half * 2 + q;
      float a1 = 0.f, a2 = 0.f;
      for (int j = g; j < 128; j += 4) {
        a1 += p1[(size_t)j * 768 + cg];
        a2 += p2[(size_t)j * 768 + cg];
      }
      ls1[g][cl] = a1;
      ls2[g][cl] = a2;
    }
  }
  __syncthreads();
  if (t < 128) {
    const float a = ((ls1[0][t] + ls1[1][t]) + (ls1[2][t] + ls1[3][t]));
    const float bb = ((ls2[0][t] + ls2[1][t]) + (ls2[2][t] + ls2[3][t]));
    const float m = a * (1.0f / 16384.f);
    const float v = bb * (1.0f / 16384.f) - m * m;
    smu[t] = m;
    sriv[t] = 1.0f / sqrtf(v + 1e-5f);
  }
  __syncthreads();
  float acc[16] = {};
  const int lrow = t >> 4, lf = (t & 15) << 2;
  const int c = (h << 6) + lf;
  const int ck = 256 + c, cv = 512 + c;
  const float4 kmu = *(const float4*)&smu[lf];
  const float4 krv = *(const float4*)&sriv[lf];
  const float4 vmu = *(const float4*)&smu[64 + lf];
  const float4 vrv = *(const float4*)&sriv[64 + lf];
  const float4 kg4 = *(const float4*)(kg + c);
  const float4 kb4 = *(const float4*)(kb + c);
  const float4 vg4 = *(const float4*)(vg + c);
  const float4 vb4 = *(const float4*)(vb + c);
  for (int n0 = sp * 256; n0 < sp * 256 + 256; n0 += 16) {
    const size_t rowb = (size_t)(b * NN + n0 + lrow) * 768;
    const float4 kq = *(const float4*)(Yq + rowb + ck);
    const float4 vq = *(const float4*)(Yq + rowb + cv);
    __syncthreads();
    ks[lrow][lf + 0] = ((kq.x - kmu.x) * krv.x * kg4.x + kb4.x >= 1.0f) ? 1.f : 0.f;
    ks[lrow][lf + 1] = ((kq.y - kmu.y) * krv.y * kg4.y + kb4.y >= 1.0f) ? 1.f : 0.f;
    ks[lrow][lf + 2] = ((kq.z - kmu.z) * krv.z * kg4.z + kb4.z >= 1.0f) ? 1.f : 0.f;
    ks[lrow][lf + 3] = ((kq.w - kmu.w) * krv.w * kg4.w + kb4.w >= 1.0f) ? 1.f : 0.f;
    vs[lrow][lf + 0] = ((vq.x - vmu.x) * vrv.x * vg4.x + vb4.x >= 1.0f) ? 1.f : 0.f;
    vs[lrow][lf + 1] = ((vq.y - vmu.y) * vrv.y * vg4.y + vb4.y >= 1.0f) ? 1.f : 0.f;
    vs[lrow][lf + 2] = ((vq.z - vmu.z) * vrv.z * vg4.z + vb4.z >= 1.0f) ? 1.f : 0.f;
    vs[lrow][lf + 3] = ((vq.w - vmu.w) * vrv.w * vg4.w + vb4.w >= 1.0f) ? 1.f : 0.f;
    __syncthreads();
#pragma unroll
    for (int nn = 0; nn < 16; ++nn) {
      const float vv = vs[nn][e];
#pragma unroll
      for (int i = 0; i < 16; ++i) acc[i] += ks[nn][(gq << 4) + i] * vv;
    }
  }
  float* mp = Mpart + ((size_t)bh * 8 + sp) * 4096;
#pragma unroll
  for (int i = 0; i < 16; ++i) mp[((gq << 4) + i) * 64 + e] = acc[i];
}

__global__ __launch_bounds__(256) void attn_kv_reduce(
    const float* __restrict__ Mpart, float* __restrict__ M) {
  const int i = blockIdx.x * 256 + threadIdx.x;
  const int bh = i >> 12, j = i & 4095;
  float s = 0.f;
#pragma unroll
  for (int sp = 0; sp < 8; ++sp)
    s += Mpart[((size_t)bh * 8 + sp) * 4096 + j];
  M[i] = s;
}

// o = 0.125 * q @ M. q spikes inline from Yq with q-channel stats computed
// inline from p1/p2 (bn_stats2-exact order). Output 1-term f16 (width 256).
__global__ __launch_bounds__(256) void attn_qm(const float* __restrict__ Yq,
    const float* __restrict__ p1, const float* __restrict__ p2,
    const float* __restrict__ qg, const float* __restrict__ qb,
    const float* __restrict__ M, u16* __restrict__ O1) {
  const int h = blockIdx.x;
  const int r0 = blockIdx.y << 6;
  const int b = blockIdx.y >> 5;
  const int t = threadIdx.x;
  const int e = t & 63, rg = t >> 6;
  __shared__ float Ms[64][64];
  __shared__ float qs[64][64];
  __shared__ float ls1[4][64], ls2[4][64];
  __shared__ float smu[64], sriv[64];
  // --- q-channel stats (group = wave index) ---
  {
    const int cg = (h << 6) + e;
    float a1 = 0.f, a2 = 0.f;
    for (int j = rg; j < 128; j += 4) {
      a1 += p1[(size_t)j * 768 + cg];
      a2 += p2[(size_t)j * 768 + cg];
    }
    ls1[rg][e] = a1;
    ls2[rg][e] = a2;
  }
  const float* Mb = M + ((size_t)(b * 4 + h) << 12);
  for (int i = t; i < 4096; i += 256) ((float*)Ms)[i] = Mb[i];
  __syncthreads();
  if (t < 64) {
    const float a = ((ls1[0][t] + ls1[1][t]) + (ls1[2][t] + ls1[3][t]));
    const float bb = ((ls2[0][t] + ls2[1][t]) + (ls2[2][t] + ls2[3][t]));
    const float m = a * (1.0f / 16384.f);
    const float v = bb * (1.0f / 16384.f) - m * m;
    smu[t] = m;
    sriv[t] = 1.0f / sqrtf(v + 1e-5f);
  }
  __syncthreads();
  const int c = (h << 6) + e;
  const float qmu = smu[e], qrv = sriv[e], qgg = qg[c], qbb = qb[c];
  for (int rl = rg; rl < 64; rl += 4) {
    const float y = Yq[(size_t)(r0 + rl) * 768 + c];
    qs[rl][e] = ((y - qmu) * qrv * qgg + qbb >= 1.0f) ? 1.f : 0.f;
  }
  __syncthreads();
  for (int rl = rg; rl < 64; rl += 4) {
    float acc = 0.f;
#pragma unroll
    for (int d = 0; d < 64; ++d) acc += qs[rl][d] * Ms[d][e];
    O1[(size_t)(r0 + rl) * 256 + (h << 6) + e] = f2h(0.125f * acc);
  }
}

// ---------------------------------------------------------------------------
extern "C" void kernel_launch(void* const* d_in, const int* in_sizes, int n_in,
                              void* d_out, int out_size, void* d_ws,
                              size_t ws_size, hipStream_t stream) {
  const float* x    = (const float*)d_in[0];
  const float* ln1g = (const float*)d_in[1];
  const float* ln1b = (const float*)d_in[2];
  const float* wq   = (const float*)d_in[3];
  const float* qg   = (const float*)d_in[4];
  const float* qb   = (const float*)d_in[5];
  const float* wk   = (const float*)d_in[6];
  const float* kg   = (const float*)d_in[7];
  const float* kb   = (const float*)d_in[8];
  const float* wv   = (const float*)d_in[9];
  const float* vg   = (const float*)d_in[10];
  const float* vb   = (const float*)d_in[11];
  const float* wo   = (const float*)d_in[12];
  const float* ln2g = (const float*)d_in[13];
  const float* ln2b = (const float*)d_in[14];
  const float* w1   = (const float*)d_in[15];
  const float* b1g  = (const float*)d_in[16];
  const float* b1b  = (const float*)d_in[17];
  const float* w2   = (const float*)d_in[18];
  const float* b2g  = (const float*)d_in[19];
  const float* b2b  = (const float*)d_in[20];
  float* out = (float*)d_out;
  char* ws = (char*)d_ws;
  const size_t MB = 1u << 20;
  u16*   h1s   = (u16*)(ws);               // [0,16)
  float* Yq    = (float*)(ws + 16 * MB);   // [16,64)  R x 768 fp32
  float* Mpart = (float*)(ws + 88 * MB);   // [88,92)  4 MB
  float* Mful  = (float*)(ws + 96 * MB);   // [96,96.5)
  u16*   o16   = (u16*)(ws);               // [0,8)    overlays h1s
  u16*   h2_16 = (u16*)(ws + 16 * MB);     // [16,24)  overlays Yq
  u16*   Ym16  = (u16*)(ws + 32 * MB);     // [32,64)  R x 1024 f16
  u16*   Y2    = (u16*)(ws + 64 * MB);     // [64,72)  R x 256 f16
  u16*   Wqkv  = (u16*)(ws + 129 * MB);    // 768 x 768 f16
  u16*   wo2   = (u16*)(ws + 131 * MB);    // 256 x 256 f16
  u16*   w12   = (u16*)(ws + 132 * MB);    // 1024 x 256 f16
  u16*   w22   = (u16*)(ws + 134 * MB);    // 256 x 1024 f16
  float* p1    = (float*)(ws + 135 * MB);
  float* p2    = (float*)(ws + 136 * MB);
  float* mu    = (float*)(ws + 137 * MB);
  float* rinv  = (float*)(ws + 137 * MB + 32768);
  float* sc1   = (float*)(ws + 137 * MB + 65536);
  float* sh1   = (float*)(ws + 137 * MB + 65536 + 4096);

  const dim3 blk(256);
  const dim3 blk512(512);

  // 0-1. weight splits + LN1 in one dispatch
  init_all<<<7168, blk, 0, stream>>>(wq, wk, wv, wo, w1, w2, Wqkv, wo2, w12,
                                     w22, x, ln1g, ln1b, h1s);

  // 2. Fused QKV projection (3-term, K'=768)
  gemm_sp<128, 192, 2, 4, 1, 4, 0, 0><<<dim3(4, 128), blk512, 0, stream>>>(
      h1s, 512, Wqkv, 768, nullptr, Yq, 768, p1, p2, nullptr, nullptr, nullptr);

  // 3-5. attention (k/v and q stats computed inline from p1/p2)
  attn_kv<<<dim3(32, 8), blk, 0, stream>>>(Yq, p1, p2, kg, kb, vg, vb, Mpart);
  attn_kv_reduce<<<512, blk, 0, stream>>>(Mpart, Mful);
  attn_qm<<<dim3(4, RR / 64), blk, 0, stream>>>(Yq, p1, p2, qg, qb, Mful, o16);

  // 6. x2 = x + o @ wo^T -> out AND h2 = f16(LN2(x2))
  gemm_sp<64, 256, 2, 4, 0, 4, 0, 1><<<dim3(1, 256), blk512, 0, stream>>>(
      o16, 256, wo2, 256, x, out, 256, nullptr, nullptr, ln2g, ln2b, h2_16);

  // 7-8. MLP1 (1-term, K'=256, f16 out) + stats (with sc/sh for fused spike)
  gemm_sp<128, 128, 2, 4, 1, 4, 1, 0><<<dim3(8, 128), blk512, 0, stream>>>(
      h2_16, 256, w12, 256, nullptr, Ym16, 1024, p1, p2, nullptr, nullptr,
      nullptr);
  bn_stats2<<<16, blk, 0, stream>>>(p1, p2, mu, rinv, 1024, 128, b1g, b1b,
                                    sc1, sh1);

  // 9-11. MLP2 with fused A-spike + BN + add
  gemm_mlp2f<<<dim3(2, 256), blk512, 0, stream>>>(Ym16, w22, sc1, sh1, Y2,
                                                  p1, p2);
  bn_stats2<<<4, blk, 0, stream>>>(p1, p2, mu, rinv, 256, 256, nullptr,
                                   nullptr, nullptr, nullptr);
  bn_spike_add_h16<<<4096, blk, 0, stream>>>(Y2, mu, rinv, b2g, b2b, out, 256);
}

// Round 20
// 163.634 us; speedup vs baseline: 1.2049x; 1.2049x over previous
//
#include <hip/hip_runtime.h>
#include <cstddef>
#include <cstdint>

#define RR 16384   // B*N rows
#define CC 256
#define NN 2048

typedef __attribute__((ext_vector_type(8))) _Float16 h8;
typedef __attribute__((ext_vector_type(4))) float float4v;
typedef __attribute__((ext_vector_type(8))) unsigned short u16x8;
typedef unsigned short u16;

__device__ inline float h2f(u16 u) {
  return (float)__builtin_bit_cast(_Float16, u);
}
__device__ inline u16 f2h(float f) {
  return __builtin_bit_cast(u16, (_Float16)f);
}

// ---------------------------------------------------------------------------
// Combined init: weight splits (bid < 3072) + LN1-split (bid >= 3072).
__global__ __launch_bounds__(256) void init_all(const float* __restrict__ wq,
    const float* __restrict__ wk, const float* __restrict__ wv,
    const float* __restrict__ wo, const float* __restrict__ w1,
    const float* __restrict__ w2, u16* __restrict__ Wqkv,
    u16* __restrict__ wo2, u16* __restrict__ w12, u16* __restrict__ w22,
    const float* __restrict__ x, const float* __restrict__ ln1g,
    const float* __restrict__ ln1b, u16* __restrict__ h1s) {
  const int bid = blockIdx.x;
  if (bid < 768) {  // QKV 3-term, K=256
    const float* W = (bid < 256) ? wq : (bid < 512) ? wk : wv;
    const int rowoff = (bid >> 8) << 8;
    const int li = (bid & 255) * 256 + threadIdx.x;
    const int o = li >> 8, k = li & 255;
    const float w = W[li];
    const u16 h1 = f2h(w);
    const u16 h2 = f2h(w - h2f(h1));
    u16* base = Wqkv + (size_t)(o + rowoff) * 768;
    base[k] = h1; base[256 + k] = h1; base[512 + k] = h2;
  } else if (bid < 1024) {  // wo 1-term
    const int li = (bid - 768) * 256 + threadIdx.x;
    wo2[li] = f2h(wo[li]);
  } else if (bid < 2048) {  // w1 1-term
    const int li = (bid - 1024) * 256 + threadIdx.x;
    w12[li] = f2h(w1[li]);
  } else if (bid < 3072) {  // w2 1-term
    const int li = (bid - 2048) * 256 + threadIdx.x;
    w22[li] = f2h(w2[li]);
  } else {  // LN1 -> split f16 [hi|lo]
    const int wave = threadIdx.x >> 6, lane = threadIdx.x & 63;
    const int row = ((bid - 3072) << 2) + wave;
    const float4 v = ((const float4*)(x + (size_t)row * CC))[lane];
    float s1 = v.x + v.y + v.z + v.w;
    float s2 = v.x * v.x + v.y * v.y + v.z * v.z + v.w * v.w;
#pragma unroll
    for (int o = 32; o > 0; o >>= 1) {
      s1 += __shfl_xor(s1, o);
      s2 += __shfl_xor(s2, o);
    }
    const float mu = s1 * (1.0f / CC);
    const float var = s2 * (1.0f / CC) - mu * mu;
    const float rs = 1.0f / sqrtf(var + 1e-5f);
    const float4 gg = ((const float4*)ln1g)[lane];
    const float4 bb = ((const float4*)ln1b)[lane];
    float o4[4];
    o4[0] = (v.x - mu) * rs * gg.x + bb.x;
    o4[1] = (v.y - mu) * rs * gg.y + bb.y;
    o4[2] = (v.z - mu) * rs * gg.z + bb.z;
    o4[3] = (v.w - mu) * rs * gg.w + bb.w;
    ushort4 hi, lo;
    hi.x = f2h(o4[0]); lo.x = f2h(o4[0] - h2f(hi.x));
    hi.y = f2h(o4[1]); lo.y = f2h(o4[1] - h2f(hi.y));
    hi.z = f2h(o4[2]); lo.z = f2h(o4[2] - h2f(hi.z));
    hi.w = f2h(o4[3]); lo.w = f2h(o4[3] - h2f(hi.w));
    *(ushort4*)(h1s + (size_t)row * 512 + (lane << 2)) = hi;
    *(ushort4*)(h1s + (size_t)row * 512 + 256 + (lane << 2)) = lo;
  }
}

// ---------------------------------------------------------------------------
// 8-wave 2-phase MFMA GEMM (proven skeleton).
template <int BM, int BN, int WM, int WN, int STATS, int MINW, int OUTF16,
          int LNFUSE>
__global__ __launch_bounds__(512, MINW) void gemm_sp(
    const u16* __restrict__ A, int AW,
    const u16* __restrict__ W2, int K2,
    const float* __restrict__ resid, void* __restrict__ Yv, int O,
    float* __restrict__ p1, float* __restrict__ p2,
    const float* __restrict__ lng, const float* __restrict__ lnb,
    u16* __restrict__ h2out) {
  constexpr int FM = BM / (WM * 16);
  constexpr int FN = BN / (WN * 16);
  constexpr int LA = BM / 64;
  constexpr int LB = BN / 64;
  constexpr int NL = LA + LB;
  static_assert(WM * WN == 8, "8 waves");
  static_assert(NL == 3 || NL == 4 || NL == 5 || NL == 7 || NL == 8,
                "vmcnt literal");
  static_assert(!LNFUSE || (BM == 64 && BN == 256), "LNFUSE tile");
  __shared__ __align__(16) u16 As[2][BM * 64];
  __shared__ __align__(16) u16 Bs[2][BN * 64];
  const int tid = threadIdx.x;
  const int lane = tid & 63, wid = tid >> 6;
  const int wr = wid / WN, wc = wid % WN;
  const int gx = gridDim.x;
  const int lid = blockIdx.y * gx + blockIdx.x;
  const int chunk = (gx * gridDim.y) >> 3;
  const int nid = (lid & 7) * chunk + (lid >> 3);
  const int bx = nid % gx, by = nid / gx;
  const int r0 = by * BM, o0 = bx * BN;
  const int lrow = tid >> 3;
  const int lce = ((tid & 7) ^ ((tid >> 3) & 7)) << 3;

  auto STAGE = [&](int buf, int kAs, int k0s) {
#pragma unroll
    for (int i = 0; i < LA; ++i) {
      const u16* srcA = A + (size_t)(r0 + i * 64 + lrow) * AW + kAs + lce;
      __builtin_amdgcn_global_load_lds(
          (const __attribute__((address_space(1))) void*)srcA,
          (__attribute__((address_space(3))) void*)&As[buf][(i * 64 + wid * 8) * 64],
          16, 0, 0);
    }
#pragma unroll
    for (int i = 0; i < LB; ++i) {
      const u16* srcB = W2 + (size_t)(o0 + i * 64 + lrow) * K2 + k0s + lce;
      __builtin_amdgcn_global_load_lds(
          (const __attribute__((address_space(1))) void*)srcB,
          (__attribute__((address_space(3))) void*)&Bs[buf][(i * 64 + wid * 8) * 64],
          16, 0, 0);
    }
  };

  float4v acc[FM][FN] = {};
  STAGE(0, 0, 0);
  int kA = 0, cur = 0;
  for (int k0 = 0; k0 < K2; k0 += 64) {
    const int kAn = (kA + 64) & (AW - 1);
    if (k0 + 64 < K2) {
      STAGE(cur ^ 1, kAn, k0 + 64);
      if constexpr (NL == 3)
        asm volatile("s_waitcnt vmcnt(3)\n\ts_barrier" ::: "memory");
      else if constexpr (NL == 4)
        asm volatile("s_waitcnt vmcnt(4)\n\ts_barrier" ::: "memory");
      else if constexpr (NL == 5)
        asm volatile("s_waitcnt vmcnt(5)\n\ts_barrier" ::: "memory");
      else if constexpr (NL == 7)
        asm volatile("s_waitcnt vmcnt(7)\n\ts_barrier" ::: "memory");
      else
        asm volatile("s_waitcnt vmcnt(8)\n\ts_barrier" ::: "memory");
    } else {
      asm volatile("s_waitcnt vmcnt(0)\n\ts_barrier" ::: "memory");
    }
#pragma unroll
    for (int kk = 0; kk < 2; ++kk) {
      h8 a[FM], b[FN];
      const int ch0 = (kk << 2) + (lane >> 4);
      const int chs = ch0 ^ (lane & 7);
#pragma unroll
      for (int m = 0; m < FM; ++m) {
        const int R = wr * (FM * 16) + m * 16 + (lane & 15);
        a[m] = *(const h8*)&As[cur][R * 64 + chs * 8];
      }
#pragma unroll
      for (int n = 0; n < FN; ++n) {
        const int Rb = wc * (FN * 16) + n * 16 + (lane & 15);
        b[n] = *(const h8*)&Bs[cur][Rb * 64 + chs * 8];
      }
#pragma unroll
      for (int m = 0; m < FM; ++m)
#pragma unroll
        for (int n = 0; n < FN; ++n)
          acc[m][n] = __builtin_amdgcn_mfma_f32_16x16x32_f16(a[m], b[n], acc[m][n], 0, 0, 0);
    }
    asm volatile("s_waitcnt lgkmcnt(0)\n\ts_barrier" ::: "memory");
    kA = kAn; cur ^= 1;
  }
  const int crow = (lane >> 4) << 2, ccol = lane & 15;
  float* ft = (float*)Bs;  // LNFUSE: 64x256 fp32 tile = 64KB
#pragma unroll
  for (int m = 0; m < FM; ++m)
#pragma unroll
    for (int n = 0; n < FN; ++n)
#pragma unroll
      for (int j = 0; j < 4; ++j) {
        const int lr = wr * (FM * 16) + (m << 4) + crow + j;
        const int lc = wc * (FN * 16) + (n << 4) + ccol;
        const size_t idx = (size_t)(r0 + lr) * O + o0 + lc;
        float v = acc[m][n][j];
        if constexpr (OUTF16) {
          ((u16*)Yv)[idx] = f2h(v);
        } else {
          if (resid) v += resid[idx];
          ((float*)Yv)[idx] = v;
        }
        if constexpr (LNFUSE) ft[lr * 256 + lc] = v;
      }
  if constexpr (LNFUSE) {
    __syncthreads();
    const int rr0 = wid << 3;
    const float4 gg = ((const float4*)lng)[lane];
    const float4 bb = ((const float4*)lnb)[lane];
#pragma unroll
    for (int rr = 0; rr < 8; ++rr) {
      const int r = rr0 + rr;
      const float4 v = ((const float4*)ft)[r * 64 + lane];
      float s1 = v.x + v.y + v.z + v.w;
      float s2 = v.x * v.x + v.y * v.y + v.z * v.z + v.w * v.w;
#pragma unroll
      for (int o = 32; o > 0; o >>= 1) {
        s1 += __shfl_xor(s1, o);
        s2 += __shfl_xor(s2, o);
      }
      const float mu = s1 * (1.0f / CC);
      const float var = s2 * (1.0f / CC) - mu * mu;
      const float rs = 1.0f / sqrtf(var + 1e-5f);
      ushort4 hh;
      hh.x = f2h((v.x - mu) * rs * gg.x + bb.x);
      hh.y = f2h((v.y - mu) * rs * gg.y + bb.y);
      hh.z = f2h((v.z - mu) * rs * gg.z + bb.z);
      hh.w = f2h((v.w - mu) * rs * gg.w + bb.w);
      *(ushort4*)(h2out + (size_t)(r0 + r) * 256 + (lane << 2)) = hh;
    }
  }
  if (STATS) {
    float s1[FN], s2[FN];
#pragma unroll
    for (int n = 0; n < FN; ++n) {
      s1[n] = 0.f; s2[n] = 0.f;
#pragma unroll
      for (int m = 0; m < FM; ++m)
#pragma unroll
        for (int j = 0; j < 4; ++j) {
          const float v = acc[m][n][j];
          s1[n] += v; s2[n] += v * v;
        }
    }
#pragma unroll
    for (int n = 0; n < FN; ++n) {
      s1[n] += __shfl_xor(s1[n], 16); s1[n] += __shfl_xor(s1[n], 32);
      s2[n] += __shfl_xor(s2[n], 16); s2[n] += __shfl_xor(s2[n], 32);
    }
    float* sb = (float*)As;
    __syncthreads();
    if (lane < 16) {
#pragma unroll
      for (int n = 0; n < FN; ++n) {
        const int cl = wc * (FN * 16) + n * 16 + lane;
        sb[wr * BN + cl] = s1[n];
        sb[WM * BN + wr * BN + cl] = s2[n];
      }
    }
    __syncthreads();
    if (tid < BN) {
      float a = 0.f, b = 0.f;
#pragma unroll
      for (int w = 0; w < WM; ++w) {
        a += sb[w * BN + tid];
        b += sb[WM * BN + w * BN + tid];
      }
      p1[(size_t)by * O + o0 + tid] = a;
      p2[(size_t)by * O + o0 + tid] = b;
    }
  }
}

// ---------------------------------------------------------------------------
// MLP2 with FUSED A-side spike (round-16 proven).
__global__ __launch_bounds__(512, 4) void gemm_mlp2f(
    const u16* __restrict__ A, const u16* __restrict__ W2,
    const float* __restrict__ sc, const float* __restrict__ sh,
    u16* __restrict__ Y, float* __restrict__ p1, float* __restrict__ p2) {
  constexpr int BM = 64, BN = 128, WM = 2, WN = 4, K2 = 1024;
  constexpr int FM = 2, FN = 2;
  __shared__ __align__(16) u16 As[2][BM * 64];
  __shared__ __align__(16) u16 Bs[2][BN * 64];
  const int tid = threadIdx.x;
  const int lane = tid & 63, wid = tid >> 6;
  const int wr = wid / WN, wc = wid % WN;
  const int gx = gridDim.x;
  const int lid = blockIdx.y * gx + blockIdx.x;
  const int chunk = (gx * gridDim.y) >> 3;
  const int nid = (lid & 7) * chunk + (lid >> 3);
  const int bx = nid % gx, by = nid / gx;
  const int r0 = by * BM, o0 = bx * BN;
  const int lrow = tid >> 3;
  const int cs = (tid & 7) ^ (lrow & 7);

  u16x8 a1, a2;
  float4 c01, c11, s01, s11, c02, c12, s02, s12;
  auto LOADA = [&](int k0s, u16x8& av, float4& c0, float4& c1, float4& s0,
                   float4& s1) {
    av = *(const u16x8*)(A + (size_t)(r0 + lrow) * 1024 + k0s + cs * 8);
    const int ch = k0s + cs * 8;
    c0 = *(const float4*)(sc + ch);
    c1 = *(const float4*)(sc + ch + 4);
    s0 = *(const float4*)(sh + ch);
    s1 = *(const float4*)(sh + ch + 4);
  };
  auto STAGE_B = [&](int buf, int k0s) {
#pragma unroll
    for (int i = 0; i < 2; ++i) {
      const u16* srcB = W2 + (size_t)(o0 + i * 64 + lrow) * K2 + k0s +
                        (((tid & 7) ^ (lrow & 7)) << 3);
      __builtin_amdgcn_global_load_lds(
          (const __attribute__((address_space(1))) void*)srcB,
          (__attribute__((address_space(3))) void*)&Bs[buf][(i * 64 + wid * 8) * 64],
          16, 0, 0);
    }
  };
  auto WRITEA = [&](int buf, u16x8 av, float4 c0, float4 c1, float4 s0,
                    float4 s1) {
    u16x8 sp;
    sp[0] = (h2f(av[0]) * c0.x + s0.x >= 1.0f) ? (u16)0x3C00 : (u16)0;
    sp[1] = (h2f(av[1]) * c0.y + s0.y >= 1.0f) ? (u16)0x3C00 : (u16)0;
    sp[2] = (h2f(av[2]) * c0.z + s0.z >= 1.0f) ? (u16)0x3C00 : (u16)0;
    sp[3] = (h2f(av[3]) * c0.w + s0.w >= 1.0f) ? (u16)0x3C00 : (u16)0;
    sp[4] = (h2f(av[4]) * c1.x + s1.x >= 1.0f) ? (u16)0x3C00 : (u16)0;
    sp[5] = (h2f(av[5]) * c1.y + s1.y >= 1.0f) ? (u16)0x3C00 : (u16)0;
    sp[6] = (h2f(av[6]) * c1.z + s1.z >= 1.0f) ? (u16)0x3C00 : (u16)0;
    sp[7] = (h2f(av[7]) * c1.w + s1.w >= 1.0f) ? (u16)0x3C00 : (u16)0;
    *(u16x8*)&As[buf][lrow * 64 + (tid & 7) * 8] = sp;
  };

  float4v acc[FM][FN] = {};
  LOADA(0, a1, c01, c11, s01, s11);
  STAGE_B(0, 0);
  int cur = 0;
  for (int k0 = 0; k0 < K2; k0 += 64) {
    if (k0 + 64 < K2) {
      LOADA(k0 + 64, a2, c02, c12, s02, s12);
      STAGE_B(cur ^ 1, k0 + 64);
      asm volatile("s_waitcnt vmcnt(7)\n\ts_barrier" ::: "memory");
    } else {
      asm volatile("s_waitcnt vmcnt(0)\n\ts_barrier" ::: "memory");
    }
    WRITEA(cur, a1, c01, c11, s01, s11);
    asm volatile("s_waitcnt lgkmcnt(0)\n\ts_barrier" ::: "memory");
#pragma unroll
    for (int kk = 0; kk < 2; ++kk) {
      h8 a[FM], b[FN];
      const int ch0 = (kk << 2) + (lane >> 4);
      const int chs = ch0 ^ (lane & 7);
#pragma unroll
      for (int m = 0; m < FM; ++m) {
        const int R = wr * 32 + m * 16 + (lane & 15);
        a[m] = *(const h8*)&As[cur][R * 64 + chs * 8];
      }
#pragma unroll
      for (int n = 0; n < FN; ++n) {
        const int Rb = wc * 32 + n * 16 + (lane & 15);
        b[n] = *(const h8*)&Bs[cur][Rb * 64 + chs * 8];
      }
#pragma unroll
      for (int m = 0; m < FM; ++m)
#pragma unroll
        for (int n = 0; n < FN; ++n)
          acc[m][n] = __builtin_amdgcn_mfma_f32_16x16x32_f16(a[m], b[n], acc[m][n], 0, 0, 0);
    }
    asm volatile("s_waitcnt lgkmcnt(0)\n\ts_barrier" ::: "memory");
    cur ^= 1;
    a1 = a2; c01 = c02; c11 = c12; s01 = s02; s11 = s12;
  }
  const int crow = (lane >> 4) << 2, ccol = lane & 15;
#pragma unroll
  for (int m = 0; m < FM; ++m)
#pragma unroll
    for (int n = 0; n < FN; ++n)
#pragma unroll
      for (int j = 0; j < 4; ++j) {
        const size_t idx =
            (size_t)(r0 + wr * 32 + (m << 4) + crow + j) * 256 +
            o0 + wc * 32 + (n << 4) + ccol;
        Y[idx] = f2h(acc[m][n][j]);
      }
  {  // STATS
    float s1[FN], s2[FN];
#pragma unroll
    for (int n = 0; n < FN; ++n) {
      s1[n] = 0.f; s2[n] = 0.f;
#pragma unroll
      for (int m = 0; m < FM; ++m)
#pragma unroll
        for (int j = 0; j < 4; ++j) {
          const float v = acc[m][n][j];
          s1[n] += v; s2[n] += v * v;
        }
    }
#pragma unroll
    for (int n = 0; n < FN; ++n) {
      s1[n] += __shfl_xor(s1[n], 16); s1[n] += __shfl_xor(s1[n], 32);
      s2[n] += __shfl_xor(s2[n], 16); s2[n] += __shfl_xor(s2[n], 32);
    }
    float* sb = (float*)As;
    __syncthreads();
    if (lane < 16) {
#pragma unroll
      for (int n = 0; n < FN; ++n) {
        const int cl = wc * 32 + n * 16 + lane;
        sb[wr * BN + cl] = s1[n];
        sb[WM * BN + wr * BN + cl] = s2[n];
      }
    }
    __syncthreads();
    if (tid < BN) {
      float a = 0.f, b = 0.f;
#pragma unroll
      for (int w = 0; w < WM; ++w) {
        a += sb[w * BN + tid];
        b += sb[WM * BN + w * BN + tid];
      }
      p1[(size_t)by * 256 + o0 + tid] = a;
      p2[(size_t)by * 256 + o0 + tid] = b;
    }
  }
}

// ---------------------------------------------------------------------------
// BN stats pass 2 (parallel). Optionally emits sc = rinv*g, sh = b - mu*rinv*g.
__global__ __launch_bounds__(256) void bn_stats2(const float* __restrict__ p1,
    const float* __restrict__ p2, float* __restrict__ mu,
    float* __restrict__ rinv, int O, int npanels,
    const float* __restrict__ g, const float* __restrict__ b,
    float* __restrict__ sc, float* __restrict__ sh) {
  const int c0 = blockIdx.x << 6;
  const int c = threadIdx.x & 63;
  const int jg = threadIdx.x >> 6;   // 0..3
  float s1 = 0.f, s2 = 0.f;
#pragma unroll 4
  for (int j = jg; j < npanels; j += 4) {
    s1 += p1[(size_t)j * O + c0 + c];
    s2 += p2[(size_t)j * O + c0 + c];
  }
  __shared__ float sb[8][64];
  sb[jg][c] = s1;
  sb[4 + jg][c] = s2;
  __syncthreads();
  if (threadIdx.x < 64) {
    const float a = ((sb[0][c] + sb[1][c]) + (sb[2][c] + sb[3][c]));
    const float bb = ((sb[4][c] + sb[5][c]) + (sb[6][c] + sb[7][c]));
    const float m = a * (1.0f / 16384.f);
    const float v = bb * (1.0f / 16384.f) - m * m;
    const float rv = 1.0f / sqrtf(v + 1e-5f);
    mu[c0 + c] = m;
    rinv[c0 + c] = rv;
    if (sc) {
      const float scale = rv * g[c0 + c];
      sc[c0 + c] = scale;
      sh[c0 + c] = b[c0 + c] - m * scale;
    }
  }
}

// BN affine + spike (f16 Y) added into fp32 output (final residual).
__global__ __launch_bounds__(256) void bn_spike_add_h16(
    const u16* __restrict__ Y, const float* __restrict__ mu,
    const float* __restrict__ rinv, const float* __restrict__ g,
    const float* __restrict__ b, float* __restrict__ addOut, int O) {
  const int i = blockIdx.x * 256 + threadIdx.x;
  const int c = (i << 2) & (O - 1);
  const ushort4 yh = ((const ushort4*)Y)[i];
  const float4 m4 = *(const float4*)(mu + c);
  const float4 r4 = *(const float4*)(rinv + c);
  const float4 g4 = *(const float4*)(g + c);
  const float4 b4 = *(const float4*)(b + c);
  float4 o4 = ((const float4*)addOut)[i];
  o4.x += ((h2f(yh.x) - m4.x) * r4.x * g4.x + b4.x >= 1.0f) ? 1.0f : 0.0f;
  o4.y += ((h2f(yh.y) - m4.y) * r4.y * g4.y + b4.y >= 1.0f) ? 1.0f : 0.0f;
  o4.z += ((h2f(yh.z) - m4.z) * r4.z * g4.z + b4.z >= 1.0f) ? 1.0f : 0.0f;
  o4.w += ((h2f(yh.w) - m4.w) * r4.w * g4.w + b4.w >= 1.0f) ? 1.0f : 0.0f;
  ((float4*)addOut)[i] = o4;
}

// ---------------------------------------------------------------------------
// M[b,h] = K^T V (64x64), split over n into 16 partials.
__global__ __launch_bounds__(256) void attn_kv(const float* __restrict__ Yq,
    const float* __restrict__ mu, const float* __restrict__ rinv,
    const float* __restrict__ kg, const float* __restrict__ kb,
    const float* __restrict__ vg, const float* __restrict__ vb,
    float* __restrict__ Mpart) {
  const int bh = blockIdx.x, sp = blockIdx.y;
  const int b = bh >> 2, h = bh & 3;
  const int t = threadIdx.x;
  const int gq = t >> 6, e = t & 63;
  __shared__ float ks[16][64], vs[16][64];
  float acc[16] = {};
  const int lrow = t >> 4, lf = (t & 15) << 2;
  const int c = (h << 6) + lf;
  const int ck = 256 + c, cv = 512 + c;
  const float4 kmu = *(const float4*)(mu + ck);
  const float4 krv = *(const float4*)(rinv + ck);
  const float4 kg4 = *(const float4*)(kg + c);
  const float4 kb4 = *(const float4*)(kb + c);
  const float4 vmu = *(const float4*)(mu + cv);
  const float4 vrv = *(const float4*)(rinv + cv);
  const float4 vg4 = *(const float4*)(vg + c);
  const float4 vb4 = *(const float4*)(vb + c);
  for (int n0 = sp * 128; n0 < sp * 128 + 128; n0 += 16) {
    const size_t rowb = (size_t)(b * NN + n0 + lrow) * 768;
    const float4 kq = *(const float4*)(Yq + rowb + ck);
    const float4 vq = *(const float4*)(Yq + rowb + cv);
    __syncthreads();
    ks[lrow][lf + 0] = ((kq.x - kmu.x) * krv.x * kg4.x + kb4.x >= 1.0f) ? 1.f : 0.f;
    ks[lrow][lf + 1] = ((kq.y - kmu.y) * krv.y * kg4.y + kb4.y >= 1.0f) ? 1.f : 0.f;
    ks[lrow][lf + 2] = ((kq.z - kmu.z) * krv.z * kg4.z + kb4.z >= 1.0f) ? 1.f : 0.f;
    ks[lrow][lf + 3] = ((kq.w - kmu.w) * krv.w * kg4.w + kb4.w >= 1.0f) ? 1.f : 0.f;
    vs[lrow][lf + 0] = ((vq.x - vmu.x) * vrv.x * vg4.x + vb4.x >= 1.0f) ? 1.f : 0.f;
    vs[lrow][lf + 1] = ((vq.y - vmu.y) * vrv.y * vg4.y + vb4.y >= 1.0f) ? 1.f : 0.f;
    vs[lrow][lf + 2] = ((vq.z - vmu.z) * vrv.z * vg4.z + vb4.z >= 1.0f) ? 1.f : 0.f;
    vs[lrow][lf + 3] = ((vq.w - vmu.w) * vrv.w * vg4.w + vb4.w >= 1.0f) ? 1.f : 0.f;
    __syncthreads();
#pragma unroll
    for (int nn = 0; nn < 16; ++nn) {
      const float vv = vs[nn][e];
#pragma unroll
      for (int i = 0; i < 16; ++i) acc[i] += ks[nn][(gq << 4) + i] * vv;
    }
  }
  float* mp = Mpart + ((size_t)bh * 16 + sp) * 4096;
#pragma unroll
  for (int i = 0; i < 16; ++i) mp[((gq << 4) + i) * 64 + e] = acc[i];
}

__global__ __launch_bounds__(256) void attn_kv_reduce(
    const float* __restrict__ Mpart, float* __restrict__ M) {
  const int i = blockIdx.x * 256 + threadIdx.x;
  const int bh = i >> 12, j = i & 4095;
  float s = 0.f;
#pragma unroll
  for (int sp = 0; sp < 16; ++sp)
    s += Mpart[((size_t)bh * 16 + sp) * 4096 + j];
  M[i] = s;
}

// o = 0.125 * q @ M. q spikes inline from Yq. Output 1-term f16 (width 256).
__global__ __launch_bounds__(256) void attn_qm(const float* __restrict__ Yq,
    const float* __restrict__ mu, const float* __restrict__ rinv,
    const float* __restrict__ qg, const float* __restrict__ qb,
    const float* __restrict__ M, u16* __restrict__ O1) {
  const int h = blockIdx.x;
  const int r0 = blockIdx.y << 6;
  const int b = blockIdx.y >> 5;
  const int t = threadIdx.x;
  const int e = t & 63, rg = t >> 6;
  __shared__ float Ms[64][64];
  __shared__ float qs[64][64];
  const float* Mb = M + ((size_t)(b * 4 + h) << 12);
  for (int i = t; i < 4096; i += 256) ((float*)Ms)[i] = Mb[i];
  const int c = (h << 6) + e;
  const float qmu = mu[c], qrv = rinv[c], qgg = qg[c], qbb = qb[c];
  for (int rl = rg; rl < 64; rl += 4) {
    const float y = Yq[(size_t)(r0 + rl) * 768 + c];
    qs[rl][e] = ((y - qmu) * qrv * qgg + qbb >= 1.0f) ? 1.f : 0.f;
  }
  __syncthreads();
  for (int rl = rg; rl < 64; rl += 4) {
    float acc = 0.f;
#pragma unroll
    for (int d = 0; d < 64; ++d) acc += qs[rl][d] * Ms[d][e];
    O1[(size_t)(r0 + rl) * 256 + (h << 6) + e] = f2h(0.125f * acc);
  }
}

// ---------------------------------------------------------------------------
extern "C" void kernel_launch(void* const* d_in, const int* in_sizes, int n_in,
                              void* d_out, int out_size, void* d_ws,
                              size_t ws_size, hipStream_t stream) {
  const float* x    = (const float*)d_in[0];
  const float* ln1g = (const float*)d_in[1];
  const float* ln1b = (const float*)d_in[2];
  const float* wq   = (const float*)d_in[3];
  const float* qg   = (const float*)d_in[4];
  const float* qb   = (const float*)d_in[5];
  const float* wk   = (const float*)d_in[6];
  const float* kg   = (const float*)d_in[7];
  const float* kb   = (const float*)d_in[8];
  const float* wv   = (const float*)d_in[9];
  const float* vg   = (const float*)d_in[10];
  const float* vb   = (const float*)d_in[11];
  const float* wo   = (const float*)d_in[12];
  const float* ln2g = (const float*)d_in[13];
  const float* ln2b = (const float*)d_in[14];
  const float* w1   = (const float*)d_in[15];
  const float* b1g  = (const float*)d_in[16];
  const float* b1b  = (const float*)d_in[17];
  const float* w2   = (const float*)d_in[18];
  const float* b2g  = (const float*)d_in[19];
  const float* b2b  = (const float*)d_in[20];
  float* out = (float*)d_out;
  char* ws = (char*)d_ws;
  const size_t MB = 1u << 20;
  u16*   h1s   = (u16*)(ws);               // [0,16)
  float* Yq    = (float*)(ws + 16 * MB);   // [16,64)  R x 768 fp32
  float* Mpart = (float*)(ws + 88 * MB);   // [88,96)
  float* Mful  = (float*)(ws + 96 * MB);   // [96,96.5)
  u16*   o16   = (u16*)(ws);               // [0,8)    overlays h1s
  u16*   h2_16 = (u16*)(ws + 16 * MB);     // [16,24)  overlays Yq
  u16*   Ym16  = (u16*)(ws + 32 * MB);     // [32,64)  R x 1024 f16
  u16*   Y2    = (u16*)(ws + 64 * MB);     // [64,72)  R x 256 f16
  u16*   Wqkv  = (u16*)(ws + 129 * MB);    // 768 x 768 f16
  u16*   wo2   = (u16*)(ws + 131 * MB);    // 256 x 256 f16
  u16*   w12   = (u16*)(ws + 132 * MB);    // 1024 x 256 f16
  u16*   w22   = (u16*)(ws + 134 * MB);    // 256 x 1024 f16
  float* p1    = (float*)(ws + 135 * MB);
  float* p2    = (float*)(ws + 136 * MB);
  float* mu    = (float*)(ws + 137 * MB);
  float* rinv  = (float*)(ws + 137 * MB + 32768);
  float* sc1   = (float*)(ws + 137 * MB + 65536);
  float* sh1   = (float*)(ws + 137 * MB + 65536 + 4096);

  const dim3 blk(256);
  const dim3 blk512(512);

  // 0-1. weight splits + LN1 in one dispatch
  init_all<<<7168, blk, 0, stream>>>(wq, wk, wv, wo, w1, w2, Wqkv, wo2, w12,
                                     w22, x, ln1g, ln1b, h1s);

  // 2. Fused QKV projection (3-term, K'=768)
  gemm_sp<128, 192, 2, 4, 1, 4, 0, 0><<<dim3(4, 128), blk512, 0, stream>>>(
      h1s, 512, Wqkv, 768, nullptr, Yq, 768, p1, p2, nullptr, nullptr, nullptr);

  // 3. BN stats finalize (q,k,v)
  bn_stats2<<<12, blk, 0, stream>>>(p1, p2, mu, rinv, 768, 128, nullptr,
                                    nullptr, nullptr, nullptr);

  // 4-6. attention (separate reduce -> Mful; attn_qm reads reduced M)
  attn_kv<<<dim3(32, 16), blk, 0, stream>>>(Yq, mu, rinv, kg, kb, vg, vb, Mpart);
  attn_kv_reduce<<<512, blk, 0, stream>>>(Mpart, Mful);
  attn_qm<<<dim3(4, RR / 64), blk, 0, stream>>>(Yq, mu, rinv, qg, qb, Mful, o16);

  // 7. x2 = x + o @ wo^T -> out AND h2 = f16(LN2(x2))
  gemm_sp<64, 256, 2, 4, 0, 4, 0, 1><<<dim3(1, 256), blk512, 0, stream>>>(
      o16, 256, wo2, 256, x, out, 256, nullptr, nullptr, ln2g, ln2b, h2_16);

  // 8-9. MLP1 (1-term, K'=256, f16 out) + stats (with sc/sh for fused spike)
  gemm_sp<128, 128, 2, 4, 1, 4, 1, 0><<<dim3(8, 128), blk512, 0, stream>>>(
      h2_16, 256, w12, 256, nullptr, Ym16, 1024, p1, p2, nullptr, nullptr,
      nullptr);
  bn_stats2<<<16, blk, 0, stream>>>(p1, p2, mu, rinv, 1024, 128, b1g, b1b,
                                    sc1, sh1);

  // 10-12. MLP2 with fused A-spike + BN + add
  gemm_mlp2f<<<dim3(2, 256), blk512, 0, stream>>>(Ym16, w22, sc1, sh1, Y2,
                                                  p1, p2);
  bn_stats2<<<4, blk, 0, stream>>>(p1, p2, mu, rinv, 256, 256, nullptr,
                                   nullptr, nullptr, nullptr);
  bn_spike_add_h16<<<4096, blk, 0, stream>>>(Y2, mu, rinv, b2g, b2b, out, 256);
}